// Round 1
// baseline (157.166 us; speedup 1.0000x reference)
//
#include <hip/hip_runtime.h>
#include <math.h>

#define F 256
#define E 256
#define S 32

// ---------------------------------------------------------------------------
// Kernel A: M = Wq @ Wk^T  [F][F],  c = bq @ Wk^T  [F]
// grid = F+1 blocks (block F computes c), 256 threads.
// ---------------------------------------------------------------------------
__global__ __launch_bounds__(256) void prep_M(const float* __restrict__ Wq,
                                              const float* __restrict__ bq,
                                              const float* __restrict__ Wk,
                                              float* __restrict__ M,
                                              float* __restrict__ c) {
    const int i = blockIdx.x;
    const int j = threadIdx.x;
    __shared__ float row[E];
    row[j] = (i < F) ? Wq[i * E + j] : bq[j];
    __syncthreads();
    float acc = 0.f;
#pragma unroll 8
    for (int e = 0; e < E; e += 4) {
        float4 w = *reinterpret_cast<const float4*>(&Wk[j * E + e]);
        acc += row[e] * w.x + row[e + 1] * w.y + row[e + 2] * w.z + row[e + 3] * w.w;
    }
    if (i < F) M[i * F + j] = acc;
    else       c[j] = acc;
}

// ---------------------------------------------------------------------------
// Kernel B/D: out[r][:] = X[idx ? idx[r] : r][:] @ W + bias   (f32, K=N=256)
// 64x64 tile per block, 256 threads, 4x4 micro-tile per thread.
// ---------------------------------------------------------------------------
__global__ __launch_bounds__(256) void gemm_bias(const float* __restrict__ X,
                                                 const int* __restrict__ idx,
                                                 const float* __restrict__ W,
                                                 const float* __restrict__ bias,
                                                 float* __restrict__ out,
                                                 int rows) {
    __shared__ float xsT[64][68];   // [k][r], stride 68 keeps 16B alignment + spreads banks
    __shared__ float wt[64][64];    // [k][j_local]
    const int tid = threadIdx.x;
    const int tx = tid & 15, ty = tid >> 4;
    const int bn = blockIdx.x, bm = blockIdx.y;
    const int jb = bn * 64 + tx * 4;
    float acc[4][4] = {{0.f}};

    for (int k0 = 0; k0 < F; k0 += 64) {
#pragma unroll
        for (int p = 0; p < 4; ++p) {
            // stage X tile (transposed into LDS)
            const int lr = p * 16 + ty;       // local row 0..63
            const int lk = tx * 4;            // local k   0..60
            const int gr = bm * 64 + lr;
            const int grc = gr < rows ? gr : rows - 1;
            const long grow = idx ? (long)idx[grc] : (long)grc;
            float4 v = *reinterpret_cast<const float4*>(&X[grow * F + k0 + lk]);
            xsT[lk + 0][lr] = v.x; xsT[lk + 1][lr] = v.y;
            xsT[lk + 2][lr] = v.z; xsT[lk + 3][lr] = v.w;
            // stage W tile
            const int wk = p * 16 + ty;
            float4 wv = *reinterpret_cast<const float4*>(&W[(size_t)(k0 + wk) * E + bn * 64 + tx * 4]);
            *reinterpret_cast<float4*>(&wt[wk][tx * 4]) = wv;
        }
        __syncthreads();
#pragma unroll 16
        for (int k = 0; k < 64; ++k) {
            float4 a = *reinterpret_cast<const float4*>(&xsT[k][ty * 4]);
            float4 b = *reinterpret_cast<const float4*>(&wt[k][tx * 4]);
            acc[0][0] += a.x * b.x; acc[0][1] += a.x * b.y; acc[0][2] += a.x * b.z; acc[0][3] += a.x * b.w;
            acc[1][0] += a.y * b.x; acc[1][1] += a.y * b.y; acc[1][2] += a.y * b.z; acc[1][3] += a.y * b.w;
            acc[2][0] += a.z * b.x; acc[2][1] += a.z * b.y; acc[2][2] += a.z * b.z; acc[2][3] += a.z * b.w;
            acc[3][0] += a.w * b.x; acc[3][1] += a.w * b.y; acc[3][2] += a.w * b.z; acc[3][3] += a.w * b.w;
        }
        __syncthreads();
    }

    const float4 bb = *reinterpret_cast<const float4*>(&bias[jb]);
#pragma unroll
    for (int v = 0; v < 4; ++v) {
        const int r = bm * 64 + ty * 4 + v;
        if (r < rows) {
            float4 o;
            o.x = acc[v][0] + bb.x; o.y = acc[v][1] + bb.y;
            o.z = acc[v][2] + bb.z; o.w = acc[v][3] + bb.w;
            *reinterpret_cast<float4*>(&out[(size_t)r * E + jb]) = o;
        }
    }
}

// ---------------------------------------------------------------------------
// Kernel C: fused gather + scores + softmax + weighted neighbor sum.
// One block (256 thr = 4 waves) per node. qtm holds q-tilde on entry and is
// overwritten with m = sum_s attn_s * neigh_feats_s (safe: block b only
// touches row b, reads complete before the write).
// ---------------------------------------------------------------------------
__global__ __launch_bounds__(256) void attn_gather(const int* __restrict__ neigh_idx,
                                                   const float* __restrict__ id2feat,
                                                   float* __restrict__ qtm) {
    const int b = blockIdx.x;
    const int tid = threadIdx.x;
    const int lane = tid & 63;
    const int w = tid >> 6;

    __shared__ float nf[S][F];   // 32 KB: gathered neighbor rows
    __shared__ float sbuf[S];
    __shared__ float wbuf[S];

    // each lane owns features 4*lane..4*lane+3 for the score phase
    const float4 qv = *reinterpret_cast<const float4*>(&qtm[(size_t)b * F + lane * 4]);

    // load + partial score: wave w handles rows s = 8w..8w+7 (it loads the
    // same rows it scores, so no barrier needed before scoring)
#pragma unroll
    for (int ss = 0; ss < 8; ++ss) {
        const int s = w * 8 + ss;
        const int nid = neigh_idx[b * S + s];
        const float4 v = *reinterpret_cast<const float4*>(&id2feat[(size_t)nid * F + lane * 4]);
        *reinterpret_cast<float4*>(&nf[s][lane * 4]) = v;
        float p = v.x * qv.x + v.y * qv.y + v.z * qv.z + v.w * qv.w;
#pragma unroll
        for (int off = 32; off; off >>= 1) p += __shfl_xor(p, off);
        if (lane == 0) sbuf[s] = p;
    }
    __syncthreads();

    // softmax over the 32 scores (wave 0 only)
    if (tid < 64) {
        const float sc = (tid < S) ? sbuf[tid] : -INFINITY;
        float mx = sc;
#pragma unroll
        for (int off = 32; off; off >>= 1) mx = fmaxf(mx, __shfl_xor(mx, off));
        const float e = __expf(sc - mx);   // 0 for tid >= S
        float sum = e;
#pragma unroll
        for (int off = 32; off; off >>= 1) sum += __shfl_xor(sum, off);
        if (tid < S) wbuf[tid] = e / sum;
    }
    __syncthreads();

    // weighted sum: thread owns feature column `tid`
    float acc = 0.f;
#pragma unroll
    for (int s = 0; s < S; ++s) acc += wbuf[s] * nf[s][tid];
    qtm[(size_t)b * F + tid] = acc;
}

// ---------------------------------------------------------------------------
extern "C" void kernel_launch(void* const* d_in, const int* in_sizes, int n_in,
                              void* d_out, int out_size, void* d_ws, size_t ws_size,
                              hipStream_t stream) {
    const int*   nodes   = (const int*)d_in[0];
    const int*   neigh   = (const int*)d_in[1];
    const float* id2feat = (const float*)d_in[2];
    const float* Wq      = (const float*)d_in[3];
    const float* bq      = (const float*)d_in[4];
    const float* Wk      = (const float*)d_in[5];
    // d_in[6] = bk is unused: a per-row constant in the logits is
    // softmax-invariant (self column is masked, so it shifts ALL live logits).
    const float* Wv      = (const float*)d_in[7];
    const float* bv      = (const float*)d_in[8];
    float* out = (float*)d_out;
    const int B = in_sizes[0];

    float* Mbuf = (float*)d_ws;          // [F][F]
    float* cbuf = Mbuf + F * F;          // [F]
    float* qtm  = cbuf + F;              // [B][F]: q-tilde, then m (reused)

    // A: M = Wq Wk^T, c = bq Wk^T
    prep_M<<<dim3(F + 1), dim3(256), 0, stream>>>(Wq, bq, Wk, Mbuf, cbuf);
    // B: q~ = gather(id2feat, nodes) @ M + c
    gemm_bias<<<dim3(4, (B + 63) / 64), dim3(256), 0, stream>>>(id2feat, nodes, Mbuf, cbuf, qtm, B);
    // C: scores -> softmax -> m (in place over qtm)
    attn_gather<<<dim3(B), dim3(256), 0, stream>>>(neigh, id2feat, qtm);
    // D: out = m @ Wv + bv
    gemm_bias<<<dim3(4, (B + 63) / 64), dim3(256), 0, stream>>>(qtm, nullptr, Wv, bv, out, B);
}

// Round 2
// 131.017 us; speedup vs baseline: 1.1996x; 1.1996x over previous
//
#include <hip/hip_runtime.h>
#include <math.h>

#define F 256
#define E 256
#define S 32

// ---------------------------------------------------------------------------
// Kernel A: M = Wq @ Wk^T  [F][F],  c = bq @ Wk^T  [F]
// grid = F+1 blocks (block F computes c), 256 threads.
// ---------------------------------------------------------------------------
__global__ __launch_bounds__(256) void prep_M(const float* __restrict__ Wq,
                                              const float* __restrict__ bq,
                                              const float* __restrict__ Wk,
                                              float* __restrict__ M,
                                              float* __restrict__ c) {
    const int i = blockIdx.x;
    const int j = threadIdx.x;
    __shared__ float row[E];
    row[j] = (i < F) ? Wq[i * E + j] : bq[j];
    __syncthreads();
    float acc = 0.f;
#pragma unroll 8
    for (int e = 0; e < E; e += 4) {
        float4 w = *reinterpret_cast<const float4*>(&Wk[j * E + e]);
        acc += row[e] * w.x + row[e + 1] * w.y + row[e + 2] * w.z + row[e + 3] * w.w;
    }
    if (i < F) M[i * F + j] = acc;
    else       c[j] = acc;
}

// ---------------------------------------------------------------------------
// Kernel B/D: out[r][:] = X[idx ? idx[r] : r][:] @ W + bias   (f32, K=N=256)
// 64x64 tile per block, 256 threads, 4x4 micro-tile per thread.
// ---------------------------------------------------------------------------
__global__ __launch_bounds__(256) void gemm_bias(const float* __restrict__ X,
                                                 const int* __restrict__ idx,
                                                 const float* __restrict__ W,
                                                 const float* __restrict__ bias,
                                                 float* __restrict__ out,
                                                 int rows) {
    __shared__ float xsT[64][68];   // [k][r], stride 68 keeps 16B alignment + spreads banks
    __shared__ float wt[64][64];    // [k][j_local]
    const int tid = threadIdx.x;
    const int tx = tid & 15, ty = tid >> 4;
    const int bn = blockIdx.x, bm = blockIdx.y;
    const int jb = bn * 64 + tx * 4;
    float acc[4][4] = {{0.f}};

    for (int k0 = 0; k0 < F; k0 += 64) {
#pragma unroll
        for (int p = 0; p < 4; ++p) {
            // stage X tile (transposed into LDS)
            const int lr = p * 16 + ty;       // local row 0..63
            const int lk = tx * 4;            // local k   0..60
            const int gr = bm * 64 + lr;
            const int grc = gr < rows ? gr : rows - 1;
            const long grow = idx ? (long)idx[grc] : (long)grc;
            float4 v = *reinterpret_cast<const float4*>(&X[grow * F + k0 + lk]);
            xsT[lk + 0][lr] = v.x; xsT[lk + 1][lr] = v.y;
            xsT[lk + 2][lr] = v.z; xsT[lk + 3][lr] = v.w;
            // stage W tile
            const int wk = p * 16 + ty;
            float4 wv = *reinterpret_cast<const float4*>(&W[(size_t)(k0 + wk) * E + bn * 64 + tx * 4]);
            *reinterpret_cast<float4*>(&wt[wk][tx * 4]) = wv;
        }
        __syncthreads();
#pragma unroll 16
        for (int k = 0; k < 64; ++k) {
            float4 a = *reinterpret_cast<const float4*>(&xsT[k][ty * 4]);
            float4 b = *reinterpret_cast<const float4*>(&wt[k][tx * 4]);
            acc[0][0] += a.x * b.x; acc[0][1] += a.x * b.y; acc[0][2] += a.x * b.z; acc[0][3] += a.x * b.w;
            acc[1][0] += a.y * b.x; acc[1][1] += a.y * b.y; acc[1][2] += a.y * b.z; acc[1][3] += a.y * b.w;
            acc[2][0] += a.z * b.x; acc[2][1] += a.z * b.y; acc[2][2] += a.z * b.z; acc[2][3] += a.z * b.w;
            acc[3][0] += a.w * b.x; acc[3][1] += a.w * b.y; acc[3][2] += a.w * b.z; acc[3][3] += a.w * b.w;
        }
        __syncthreads();
    }

    const float4 bb = *reinterpret_cast<const float4*>(&bias[jb]);
#pragma unroll
    for (int v = 0; v < 4; ++v) {
        const int r = bm * 64 + ty * 4 + v;
        if (r < rows) {
            float4 o;
            o.x = acc[v][0] + bb.x; o.y = acc[v][1] + bb.y;
            o.z = acc[v][2] + bb.z; o.w = acc[v][3] + bb.w;
            *reinterpret_cast<float4*>(&out[(size_t)r * E + jb]) = o;
        }
    }
}

// ---------------------------------------------------------------------------
// Kernel C v2: one WAVE per node, fully register-resident, no LDS, no barriers.
//  - 32 neighbor ids arrive in one coalesced load (lane l holds id[l&31])
//  - readlane -> scalar row base -> 32 independent global_load_dwordx4 in
//    flight per wave (MLP-driven latency hiding, no idx->row chain)
//  - scores via per-row 64-lane xor-butterfly (after the butterfly every lane
//    holds every score, so softmax is computed redundantly per-lane in regs)
//  - weighted sum straight from the register-held rows
// qtm holds q-tilde on entry, is overwritten with m = sum_s attn_s * row_s.
// ---------------------------------------------------------------------------
__global__ __launch_bounds__(256) void attn_gather(const int* __restrict__ neigh_idx,
                                                   const float* __restrict__ id2feat,
                                                   float* __restrict__ qtm,
                                                   int B) {
    const int node = blockIdx.x * 4 + (threadIdx.x >> 6);
    const int lane = threadIdx.x & 63;
    if (node >= B) return;

    // one coalesced load: lane l holds neigh id (l & 31)
    const int idxv = neigh_idx[node * S + (lane & (S - 1))];
    const float4 qv = *reinterpret_cast<const float4*>(&qtm[(size_t)node * F + lane * 4]);

    // 32 independent row loads, scalar base per row
    float4 rows[S];
#pragma unroll
    for (int s = 0; s < S; ++s) {
        const int nid = __builtin_amdgcn_readlane(idxv, s);
        rows[s] = *reinterpret_cast<const float4*>(&id2feat[(size_t)nid * F + lane * 4]);
    }

    // scores: per-row dot + xor-butterfly; result is wave-uniform per s
    float ps[S];
#pragma unroll
    for (int s = 0; s < S; ++s) {
        float p = rows[s].x * qv.x + rows[s].y * qv.y + rows[s].z * qv.z + rows[s].w * qv.w;
#pragma unroll
        for (int off = 32; off; off >>= 1) p += __shfl_xor(p, off);
        ps[s] = p;
    }

    // softmax over 32 register-held scores (redundant per lane, no comms)
    float mx = ps[0];
#pragma unroll
    for (int s = 1; s < S; ++s) mx = fmaxf(mx, ps[s]);
    float sum = 0.f;
#pragma unroll
    for (int s = 0; s < S; ++s) { ps[s] = __expf(ps[s] - mx); sum += ps[s]; }
    const float inv = 1.0f / sum;

    // weighted sum from register-held rows
    float4 acc = make_float4(0.f, 0.f, 0.f, 0.f);
#pragma unroll
    for (int s = 0; s < S; ++s) {
        const float w = ps[s] * inv;
        acc.x += w * rows[s].x; acc.y += w * rows[s].y;
        acc.z += w * rows[s].z; acc.w += w * rows[s].w;
    }
    *reinterpret_cast<float4*>(&qtm[(size_t)node * F + lane * 4]) = acc;
}

// ---------------------------------------------------------------------------
extern "C" void kernel_launch(void* const* d_in, const int* in_sizes, int n_in,
                              void* d_out, int out_size, void* d_ws, size_t ws_size,
                              hipStream_t stream) {
    const int*   nodes   = (const int*)d_in[0];
    const int*   neigh   = (const int*)d_in[1];
    const float* id2feat = (const float*)d_in[2];
    const float* Wq      = (const float*)d_in[3];
    const float* bq      = (const float*)d_in[4];
    const float* Wk      = (const float*)d_in[5];
    // d_in[6] = bk is unused: a per-row constant in the logits is
    // softmax-invariant (self column is masked, so it shifts ALL live logits).
    const float* Wv      = (const float*)d_in[7];
    const float* bv      = (const float*)d_in[8];
    float* out = (float*)d_out;
    const int B = in_sizes[0];

    float* Mbuf = (float*)d_ws;          // [F][F]
    float* cbuf = Mbuf + F * F;          // [F]
    float* qtm  = cbuf + F;              // [B][F]: q-tilde, then m (reused)

    // A: M = Wq Wk^T, c = bq Wk^T
    prep_M<<<dim3(F + 1), dim3(256), 0, stream>>>(Wq, bq, Wk, Mbuf, cbuf);
    // B: q~ = gather(id2feat, nodes) @ M + c
    gemm_bias<<<dim3(4, (B + 63) / 64), dim3(256), 0, stream>>>(id2feat, nodes, Mbuf, cbuf, qtm, B);
    // C: scores -> softmax -> m (in place over qtm), one wave per node
    attn_gather<<<dim3((B + 3) / 4), dim3(256), 0, stream>>>(neigh, id2feat, qtm, B);
    // D: out = m @ Wv + bv
    gemm_bias<<<dim3(4, (B + 63) / 64), dim3(256), 0, stream>>>(qtm, nullptr, Wv, bv, out, B);
}